// Round 2
// baseline (626.626 us; speedup 1.0000x reference)
//
#include <hip/hip_runtime.h>
#include <stdint.h>

// Problem constants
#define Bz 32
#define Tz 64
#define Nz 1000
#define Cz 8
#define HGz 16
#define HLz 256
#define OUTz 24
#define Ez 16000
#define K2z 8000   // N*C (folded GEMM K)
#define Mz 2048    // B*T
#define G4z 1024   // 4*HL
#define NSz 8      // split-K count

using half8  = __attribute__((ext_vector_type(8))) _Float16;
using half4  = __attribute__((ext_vector_type(4))) _Float16;
using floatx4 = __attribute__((ext_vector_type(4))) float;

// ---- Workspace layout (bytes) ----
static const size_t OFF_IDEG   = 4096;      // fp32 [1000]
static const size_t OFF_CNT    = 73728;     // int  [1024]
static const size_t OFF_ROFF   = 77824;     // int  [1024]
static const size_t OFF_CSRS   = 86016;     // int  [16000]
static const size_t OFF_CSRW   = 151552;    // fp32 [16000]
static const size_t OFF_HLAST  = 217088;    // fp32 [32][256]
static const size_t OFF_PRE16T = 249856;    // fp16 [64][32][1024]  4,194,304
static const size_t OFF_WHH16  = 4444160;   // fp16 [1024][256]       524,288
static const size_t OFF_BGC    = 6037504;   // fp32 [1024]
static const size_t OFF_XT     = 6041600;   // fp16 [2048][8000]   32,768,000
static const size_t OFF_WC     = 38809600;  // fp16 [1024][8000]   16,384,000
static const size_t OFF_PRES   = 55193600;  // fp16 [8][2048][1024] 33,554,432
static const size_t WS_NEED    = 88748032;

__device__ __forceinline__ void gl_lds16(const void* g, void* l) {
  __builtin_amdgcn_global_load_lds(
      (__attribute__((address_space(1))) void*)(void*)g,
      (__attribute__((address_space(3))) void*)l, 16, 0, 0);
}

__device__ __forceinline__ float sigm(float x) { return 1.0f / (1.0f + __expf(-x)); }
__device__ __forceinline__ float tanhh(float x) { return 1.0f - 2.0f / (__expf(2.0f * x) + 1.0f); }

// ---------------- fused GCN prep: deg, norm, CSR (one WG, LDS atomics + LDS scan) ----------------
__global__ void __launch_bounds__(1024) k_prep(const int* __restrict__ ei,
                                               const float* __restrict__ ew,
                                               float* __restrict__ ideg,
                                               int* __restrict__ cntg,
                                               int* __restrict__ roffg,
                                               int* __restrict__ csrs,
                                               float* __restrict__ csrw) {
  __shared__ float disS[1024];   // deg, then 1/sqrt(deg)
  __shared__ int   cntS[1024];
  __shared__ int   curS[1024];
  __shared__ int   scanS[1024];
  int tid = threadIdx.x;
  disS[tid] = 1.0f;
  cntS[tid] = 0;
  __syncthreads();
  for (int e = tid; e < Ez; e += 1024) {
    int col = ei[Ez + e];
    atomicAdd(&disS[col], ew[e]);
    atomicAdd(&cntS[col], 1);
  }
  __syncthreads();
  float d = disS[tid];
  float dis = 1.0f / sqrtf(d);
  if (tid < Nz) ideg[tid] = 1.0f / d;
  __syncthreads();
  disS[tid] = dis;
  // exclusive scan of cnt
  int v0 = cntS[tid];
  scanS[tid] = v0;
  __syncthreads();
  for (int off = 1; off < 1024; off <<= 1) {
    int v = (tid >= off) ? scanS[tid - off] : 0;
    __syncthreads();
    scanS[tid] += v;
    __syncthreads();
  }
  int excl = scanS[tid] - v0;
  roffg[tid] = excl;
  cntg[tid] = v0;
  curS[tid] = excl;
  __syncthreads();
  for (int e = tid; e < Ez; e += 1024) {
    int row = ei[e], col = ei[Ez + e];
    int p = atomicAdd(&curS[col], 1);
    csrs[p] = row;
    csrw[p] = disS[row] * ew[e] * disS[col];
  }
}

// Fold W_gcn into W_ih (blocks 0..1023); blocks 1024..1151 cast Whh -> fp16.
__global__ void __launch_bounds__(256) k_fold(const float* __restrict__ Wih,
                                              const float* __restrict__ Wg,
                                              const float* __restrict__ bg,
                                              _Float16* __restrict__ wc,
                                              float* __restrict__ bgc,
                                              const float* __restrict__ Whh,
                                              _Float16* __restrict__ whh16) {
  __shared__ float wgs[Cz * HGz];
  __shared__ float bgs[HGz];
  __shared__ float red[256];
  int tid = threadIdx.x;
  int j = blockIdx.x;
  if (j >= 1024) {
    size_t i = (size_t)(j - 1024) * 256 + tid;  // 32768 half8s
    float4 a = ((const float4*)Whh)[i * 2];
    float4 b = ((const float4*)Whh)[i * 2 + 1];
    half8 h;
    h[0] = (_Float16)a.x; h[1] = (_Float16)a.y; h[2] = (_Float16)a.z; h[3] = (_Float16)a.w;
    h[4] = (_Float16)b.x; h[5] = (_Float16)b.y; h[6] = (_Float16)b.z; h[7] = (_Float16)b.w;
    ((half8*)whh16)[i] = h;
    return;
  }
  if (tid < Cz * HGz) wgs[tid] = Wg[tid];
  if (tid < HGz) bgs[tid] = bg[tid];
  __syncthreads();
  const float* row = Wih + (size_t)j * (Nz * HGz);
  float bacc = 0.f;
  for (int n = tid; n < Nz; n += 256) {
    const float* p = row + n * HGz;
    float w[16];
    float4 v0 = *(const float4*)p, v1 = *(const float4*)(p + 4);
    float4 v2 = *(const float4*)(p + 8), v3 = *(const float4*)(p + 12);
    w[0]=v0.x; w[1]=v0.y; w[2]=v0.z; w[3]=v0.w;
    w[4]=v1.x; w[5]=v1.y; w[6]=v1.z; w[7]=v1.w;
    w[8]=v2.x; w[9]=v2.y; w[10]=v2.z; w[11]=v2.w;
    w[12]=v3.x; w[13]=v3.y; w[14]=v3.z; w[15]=v3.w;
    half8 o;
#pragma unroll
    for (int c = 0; c < Cz; ++c) {
      float s = 0.f;
#pragma unroll
      for (int h = 0; h < HGz; ++h) s += w[h] * wgs[c * HGz + h];
      o[c] = (_Float16)s;
    }
#pragma unroll
    for (int h = 0; h < HGz; ++h) bacc += w[h] * bgs[h];
    *(half8*)(wc + (size_t)j * K2z + n * Cz) = o;
  }
  red[tid] = bacc;
  __syncthreads();
  for (int off = 128; off > 0; off >>= 1) {
    if (tid < off) red[tid] += red[tid + off];
    __syncthreads();
  }
  if (tid == 0) bgc[j] = red[0];
}

// xt: blocks 0..249 = batch-0 rows (ideg*x + CSR neighbor agg); blocks 250..7999 = fp16 cast of x batches 1..31.
__global__ void k_xt(const float* __restrict__ x, const float* __restrict__ ideg,
                     const int* __restrict__ roff, const int* __restrict__ cnt,
                     const int* __restrict__ csrs, const float* __restrict__ csrw,
                     _Float16* __restrict__ xt) {
  if (blockIdx.x >= 250) {
    size_t i = (size_t)(blockIdx.x - 250) * 256 + threadIdx.x;
    const float* src = x + (size_t)Tz * K2z;
    _Float16* dst = xt + (size_t)Tz * K2z;
    float4 a = ((const float4*)src)[i * 2];
    float4 b = ((const float4*)src)[i * 2 + 1];
    half8 h;
    h[0] = (_Float16)a.x; h[1] = (_Float16)a.y; h[2] = (_Float16)a.z; h[3] = (_Float16)a.w;
    h[4] = (_Float16)b.x; h[5] = (_Float16)b.y; h[6] = (_Float16)b.z; h[7] = (_Float16)b.w;
    ((half8*)dst)[i] = h;
    return;
  }
  int g = blockIdx.x * 256 + threadIdx.x;  // t*1000+n
  if (g >= Tz * Nz) return;
  int t = g / Nz, n = g % Nz;
  const float* xp = x + (size_t)g * Cz;
  float4 a = *(const float4*)xp, b = *(const float4*)(xp + 4);
  float id = ideg[n];
  float s[8] = {id*a.x, id*a.y, id*a.z, id*a.w, id*b.x, id*b.y, id*b.z, id*b.w};
  int i0 = roff[n], nc = cnt[n];
  for (int i = i0; i < i0 + nc; ++i) {
    int src = csrs[i];
    float wv = csrw[i];
    const float* q = x + ((size_t)t * Nz + src) * Cz;
    float4 u = *(const float4*)q, v = *(const float4*)(q + 4);
    s[0] += wv * u.x; s[1] += wv * u.y; s[2] += wv * u.z; s[3] += wv * u.w;
    s[4] += wv * v.x; s[5] += wv * v.y; s[6] += wv * v.z; s[7] += wv * v.w;
  }
  half8 h;
#pragma unroll
  for (int c = 0; c < 8; ++c) h[c] = (_Float16)s[c];
  *(half8*)(xt + (size_t)t * K2z + n * Cz) = h;
}

// ---------------- GEMM: preS[z][2048][1024] (fp16) = xt @ Wc^T, uneven split-K=8 ----------------
__global__ void __launch_bounds__(256) k_gemm(const _Float16* __restrict__ A,
                                              const _Float16* __restrict__ Bm,
                                              _Float16* __restrict__ Cp) {
  __shared__ _Float16 As[128 * 32];
  __shared__ _Float16 Bs[128 * 32];
  const int tid = threadIdx.x;
  const int lane = tid & 63;
  const int wave = tid >> 6;
  const int wm = wave & 1, wn = wave >> 1;
  const int quad = lane >> 4, l15 = lane & 15;
  const size_t tm = (size_t)blockIdx.x * 128;
  const size_t tn = (size_t)blockIdx.y * 128;
  const int k0 = blockIdx.z * 1024;
  const int iters = (blockIdx.z < 7) ? 32 : 26;   // 7*1024 + 832 = 8000
  _Float16* Cz_ = Cp + (size_t)blockIdx.z * Mz * G4z;
  const int srow = tid >> 2;
  const int skk = (tid & 3) * 8;
  const _Float16* gA0 = A + (tm + srow) * (size_t)K2z + k0 + skk;
  const _Float16* gA1 = gA0 + 64 * (size_t)K2z;
  const _Float16* gB0 = Bm + (tn + srow) * (size_t)K2z + k0 + skk;
  const _Float16* gB1 = gB0 + 64 * (size_t)K2z;
  _Float16* lA0 = &As[tid * 8];
  _Float16* lA1 = &As[2048 + tid * 8];
  _Float16* lB0 = &Bs[tid * 8];
  _Float16* lB1 = &Bs[2048 + tid * 8];
  floatx4 acc[4][4] = {};
  for (int kt = 0; kt < iters; ++kt) {
    __syncthreads();
    gl_lds16(gA0, lA0);
    gl_lds16(gA1, lA1);
    gl_lds16(gB0, lB0);
    gl_lds16(gB1, lB1);
    gA0 += 32; gA1 += 32; gB0 += 32; gB1 += 32;
    __syncthreads();
    half8 af[4], bf[4];
#pragma unroll
    for (int i = 0; i < 4; ++i)
      af[i] = *(const half8*)&As[(wm * 64 + i * 16 + l15) * 32 + quad * 8];
#pragma unroll
    for (int i = 0; i < 4; ++i)
      bf[i] = *(const half8*)&Bs[(wn * 64 + i * 16 + l15) * 32 + quad * 8];
#pragma unroll
    for (int mi = 0; mi < 4; ++mi)
#pragma unroll
      for (int ni = 0; ni < 4; ++ni)
        acc[mi][ni] = __builtin_amdgcn_mfma_f32_16x16x32_f16(af[mi], bf[ni], acc[mi][ni], 0, 0, 0);
  }
#pragma unroll
  for (int mi = 0; mi < 4; ++mi)
#pragma unroll
    for (int ni = 0; ni < 4; ++ni) {
      size_t r0 = tm + wm * 64 + mi * 16 + quad * 4;
      size_t cc = tn + wn * 64 + ni * 16 + l15;
#pragma unroll
      for (int q = 0; q < 4; ++q) Cz_[(r0 + q) * G4z + cc] = (_Float16)acc[mi][ni][q];
    }
}

// ---------------- reduce fp16 split-K + biases -> pre[t][batch][j] (fp16) ----------------
__global__ void k_reduce(const _Float16* __restrict__ preS, const float* __restrict__ bih,
                         const float* __restrict__ bhh, const float* __restrict__ bgc,
                         _Float16* __restrict__ preT) {
  int t = blockIdx.x;                      // 0..63
  int j = blockIdx.y * 256 + threadIdx.x;  // 0..1023
  float bias = bih[j] + bhh[j] + bgc[j];
  float v[32];
#pragma unroll
  for (int b = 0; b < 32; ++b) v[b] = bias;
  for (int s = 0; s < NSz; ++s) {
    const _Float16* base = preS + (size_t)s * Mz * G4z;
#pragma unroll
    for (int b = 0; b < 32; ++b)
      v[b] += (float)base[((size_t)b * Tz + t) * G4z + j];
  }
  // layout [t][b][j]: scalar stores, coalesced across j within each wave
#pragma unroll
  for (int b = 0; b < 32; ++b)
    preT[((size_t)t * 32 + b) * G4z + j] = (_Float16)v[b];
}

// ---------------- LSTM v3: ZERO-communication. 2 blocks x 16 complete batches ----------------
// The recurrence is batch-parallel: h_t[b] depends only on h_{t-1}[b]. Each block owns 16
// batches (M=16 = one full MFMA tile) and the ENTIRE W_hh, split: 6/8 row-tiles per wave in
// VGPRs (192 VGPR, loaded once), 2/8 in LDS (gate o, 132 KB). h double-buffered in LDS.
// Per step: no global traffic, no polls, one barrier. Gate pre-acts (preT) init the MFMA
// accumulator directly (no extra registers, no epilogue adds).
// Wave w owns hl [w*32, w*32+32) for ALL 4 gates -> pointwise is lane-local.
__global__ void __launch_bounds__(512, 2) k_lstm1(const _Float16* __restrict__ Whh16,
                                                  const _Float16* __restrict__ preT, // [t][32][1024]
                                                  float* __restrict__ hlast) {       // [32][256]
  __shared__ _Float16 Wl[8][2][16 * 264];  // [wave][ht][row16 x 264]  135168 B (gate o)
  __shared__ _Float16 hb[2][16 * 264];     // [parity][batch16][k264]   16896 B
  const int tid = threadIdx.x;
  const int w = tid >> 6;
  const int lane = tid & 63;
  const int quad = lane >> 4, l15 = lane & 15;
  const int bg = blockIdx.x;               // batch group: batches bg*16 .. bg*16+15

  // zero h (h0 = 0)
  for (int i = tid; i < 2 * 16 * 264; i += 512) ((_Float16*)hb)[i] = (_Float16)0.f;

  // LDS W: gate o (rows 768..1023), wave w's hl block, 2 tiles of 16 rows x 256 K.
  {
    const int r = lane >> 2, c4 = lane & 3;
#pragma unroll
    for (int ht = 0; ht < 2; ++ht) {
      const half8* src = (const half8*)(Whh16 + ((size_t)(768 + w * 32 + ht * 16 + r)) * 256 + c4 * 64);
      half8* dst = (half8*)&Wl[w][ht][r * 264 + c4 * 64];
#pragma unroll
      for (int u = 0; u < 8; ++u) dst[u] = src[u];
    }
  }
  // VGPR W: gates i,f,g (x ht 0/1) = 6 tiles x 8 k-chunks = 192 VGPR/lane, resident all 64 steps.
  half8 wr[6][8];
#pragma unroll
  for (int gh = 0; gh < 6; ++gh) {
    const int g = gh >> 1, ht = gh & 1;
    const _Float16* src = Whh16 + ((size_t)(g * 256 + w * 32 + ht * 16 + l15)) * 256 + quad * 8;
#pragma unroll
    for (int kt = 0; kt < 8; ++kt) wr[gh][kt] = *(const half8*)(src + kt * 32);
  }

  float cst[2][4] = {{0.f, 0.f, 0.f, 0.f}, {0.f, 0.f, 0.f, 0.f}};
  __syncthreads();

  for (int t = 0; t < Tz; ++t) {
    const int p = t & 1;
    // acc init = gate pre-activation (biases already folded by k_reduce).
    // D layout: row = quad*4+q (-> hl = w*32 + ht*16 + quad*4 + q), col = l15 (-> batch).
    floatx4 acc[8];
    {
      const _Float16* pb = preT + ((size_t)t * 32 + bg * 16 + l15) * G4z + w * 32 + quad * 4;
#pragma unroll
      for (int g = 0; g < 4; ++g)
#pragma unroll
        for (int ht = 0; ht < 2; ++ht) {
          half4 v = *(const half4*)(pb + g * 256 + ht * 16);
          floatx4 a;
          a[0] = (float)v[0]; a[1] = (float)v[1]; a[2] = (float)v[2]; a[3] = (float)v[3];
          acc[g * 2 + ht] = a;
        }
    }
    const _Float16* hrow = &hb[p][l15 * 264 + quad * 8];
    const _Float16* wl0 = &Wl[w][0][l15 * 264 + quad * 8];
    const _Float16* wl1 = &Wl[w][1][l15 * 264 + quad * 8];
#pragma unroll
    for (int kt = 0; kt < 8; ++kt) {
      half8 h8 = *(const half8*)(hrow + kt * 32);
      half8 o0 = *(const half8*)(wl0 + kt * 32);
      half8 o1 = *(const half8*)(wl1 + kt * 32);
      acc[0] = __builtin_amdgcn_mfma_f32_16x16x32_f16(wr[0][kt], h8, acc[0], 0, 0, 0);
      acc[1] = __builtin_amdgcn_mfma_f32_16x16x32_f16(wr[1][kt], h8, acc[1], 0, 0, 0);
      acc[2] = __builtin_amdgcn_mfma_f32_16x16x32_f16(wr[2][kt], h8, acc[2], 0, 0, 0);
      acc[3] = __builtin_amdgcn_mfma_f32_16x16x32_f16(wr[3][kt], h8, acc[3], 0, 0, 0);
      acc[4] = __builtin_amdgcn_mfma_f32_16x16x32_f16(wr[4][kt], h8, acc[4], 0, 0, 0);
      acc[5] = __builtin_amdgcn_mfma_f32_16x16x32_f16(wr[5][kt], h8, acc[5], 0, 0, 0);
      acc[6] = __builtin_amdgcn_mfma_f32_16x16x32_f16(o0, h8, acc[6], 0, 0, 0);
      acc[7] = __builtin_amdgcn_mfma_f32_16x16x32_f16(o1, h8, acc[7], 0, 0, 0);
    }
    // pointwise: lane-local i,f,g,o for hl = w*32+ht*16+quad*4+q, batch = bg*16+l15
    _Float16* hn_base = &hb[p ^ 1][l15 * 264 + w * 32 + quad * 4];
#pragma unroll
    for (int ht = 0; ht < 2; ++ht) {
      half4 ho;
      float hf[4];
#pragma unroll
      for (int q = 0; q < 4; ++q) {
        float gi = acc[0 * 2 + ht][q];
        float gf = acc[1 * 2 + ht][q];
        float gg = acc[2 * 2 + ht][q];
        float go = acc[6 + ht][q];
        float iv = sigm(gi), fv = sigm(gf), gv = tanhh(gg), ov = sigm(go);
        float cn = fv * cst[ht][q] + iv * gv;
        cst[ht][q] = cn;
        float hnv = ov * tanhh(cn);
        ho[q] = (_Float16)hnv;
        hf[q] = hnv;
      }
      *(half4*)(hn_base + ht * 16) = ho;
      if (t == Tz - 1) {
        float4 o4; o4.x = hf[0]; o4.y = hf[1]; o4.z = hf[2]; o4.w = hf[3];
        *(float4*)&hlast[(size_t)(bg * 16 + l15) * HLz + w * 32 + ht * 16 + quad * 4] = o4;
      }
    }
    __syncthreads();
  }
}

// out[b,o] = h_last[b,:] @ W_proj[o,:] + b_proj[o]
__global__ void k_proj(const float* __restrict__ hlast, const float* __restrict__ Wp,
                       const float* __restrict__ bp, float* __restrict__ out) {
  int idx = blockIdx.x * 256 + threadIdx.x;
  if (idx >= Bz * OUTz) return;
  int b = idx / OUTz, o = idx % OUTz;
  const float* h = hlast + (size_t)b * HLz;
  const float* wr = Wp + (size_t)o * HLz;
  float s = 0.f;
  for (int k = 0; k < HLz; k += 4) {
    float4 hv = *(const float4*)&h[k];
    float4 wv = *(const float4*)&wr[k];
    s += hv.x * wv.x + hv.y * wv.y + hv.z * wv.z + hv.w * wv.w;
  }
  out[idx] = s + bp[o];
}

extern "C" void kernel_launch(void* const* d_in, const int* in_sizes, int n_in,
                              void* d_out, int out_size, void* d_ws, size_t ws_size,
                              hipStream_t stream) {
  const float* x   = (const float*)d_in[0];
  const int*   ei  = (const int*)d_in[1];
  const float* ew  = (const float*)d_in[2];
  const float* Wg  = (const float*)d_in[3];
  const float* bg  = (const float*)d_in[4];
  const float* Wih = (const float*)d_in[5];
  const float* Whh = (const float*)d_in[6];
  const float* bih = (const float*)d_in[7];
  const float* bhh = (const float*)d_in[8];
  const float* Wp  = (const float*)d_in[9];
  const float* bp  = (const float*)d_in[10];
  float* out = (float*)d_out;
  char* ws = (char*)d_ws;
  if (ws_size < WS_NEED) return;

  float* ideg  = (float*)(ws + OFF_IDEG);
  int*   cnt   = (int*)(ws + OFF_CNT);
  int*   roff  = (int*)(ws + OFF_ROFF);
  int*   csrs  = (int*)(ws + OFF_CSRS);
  float* csrw  = (float*)(ws + OFF_CSRW);
  float* hlast = (float*)(ws + OFF_HLAST);
  _Float16* preT  = (_Float16*)(ws + OFF_PRE16T);
  _Float16* whh16 = (_Float16*)(ws + OFF_WHH16);
  float* bgc   = (float*)(ws + OFF_BGC);
  _Float16* xt    = (_Float16*)(ws + OFF_XT);
  _Float16* wc    = (_Float16*)(ws + OFF_WC);
  _Float16* preS  = (_Float16*)(ws + OFF_PRES);

  k_prep<<<1, 1024, 0, stream>>>(ei, ew, ideg, cnt, roff, csrs, csrw);
  k_fold<<<1152, 256, 0, stream>>>(Wih, Wg, bg, wc, bgc, Whh, whh16);
  k_xt<<<8000, 256, 0, stream>>>(x, ideg, roff, cnt, csrs, csrw, xt);
  k_gemm<<<dim3(16, 8, NSz), 256, 0, stream>>>(xt, wc, preS);
  k_reduce<<<dim3(Tz, 4), 256, 0, stream>>>(preS, bih, bhh, bgc, preT);
  k_lstm1<<<2, 512, 0, stream>>>(whh16, preT, hlast);
  k_proj<<<3, 256, 0, stream>>>(hlast, Wp, bp, out);
}

// Round 4
// 456.900 us; speedup vs baseline: 1.3715x; 1.3715x over previous
//
#include <hip/hip_runtime.h>
#include <stdint.h>

// Problem constants
#define Bz 32
#define Tz 64
#define Nz 1000
#define Cz 8
#define HGz 16
#define HLz 256
#define OUTz 24
#define Ez 16000
#define K2z 8000   // N*C (folded GEMM K)
#define Mz 2048    // B*T
#define G4z 1024   // 4*HL
#define NSz 8      // split-K count

using half8  = __attribute__((ext_vector_type(8))) _Float16;
using half4  = __attribute__((ext_vector_type(4))) _Float16;
using floatx4 = __attribute__((ext_vector_type(4))) float;

#define SENT 0x7E7E7E7E7E7E7E7EULL  // 4x fp16 NaN, memset-able byte 0x7E

// ---- Workspace layout (bytes) ----
static const size_t OFF_IDEG   = 4096;      // fp32 [1000]
static const size_t OFF_CNT    = 73728;     // int  [1024]
static const size_t OFF_ROFF   = 77824;     // int  [1024]
static const size_t OFF_CSRS   = 86016;     // int  [16000]
static const size_t OFF_CSRW   = 151552;    // fp32 [16000]
static const size_t OFF_HLAST  = 217088;    // fp32 [32][256]
static const size_t OFF_PRE16T = 249856;    // fp16 [64][32][1024] j'=hl*4+g   4,194,304
static const size_t OFF_WHH16  = 4444160;   // fp16 [1024][256] row'=hl*4+g     524,288
static const size_t OFF_HX     = 4968448;   // u64  [2][64][16][64]           1,048,576
static const size_t OFF_BGC    = 6037504;   // fp32 [1024]
static const size_t OFF_XT     = 6041600;   // fp16 [2048][8000]   32,768,000
static const size_t OFF_WC     = 38809600;  // fp16 [1024][8000]   16,384,000
static const size_t OFF_PRES   = 55193600;  // fp16 [8][2048][1024] 33,554,432
static const size_t WS_NEED    = 88748032;

__device__ __forceinline__ void gl_lds16(const void* g, void* l) {
  __builtin_amdgcn_global_load_lds(
      (__attribute__((address_space(1))) void*)(void*)g,
      (__attribute__((address_space(3))) void*)l, 16, 0, 0);
}

__device__ __forceinline__ float sigm(float x) { return 1.0f / (1.0f + __expf(-x)); }
__device__ __forceinline__ float tanhh(float x) { return 1.0f - 2.0f / (__expf(2.0f * x) + 1.0f); }

// ---------------- fused GCN prep: deg, norm, CSR (one WG, LDS atomics + LDS scan) ----------------
__global__ void __launch_bounds__(1024) k_prep(const int* __restrict__ ei,
                                               const float* __restrict__ ew,
                                               float* __restrict__ ideg,
                                               int* __restrict__ cntg,
                                               int* __restrict__ roffg,
                                               int* __restrict__ csrs,
                                               float* __restrict__ csrw) {
  __shared__ float disS[1024];   // deg, then 1/sqrt(deg)
  __shared__ int   cntS[1024];
  __shared__ int   curS[1024];
  __shared__ int   scanS[1024];
  int tid = threadIdx.x;
  disS[tid] = 1.0f;
  cntS[tid] = 0;
  __syncthreads();
  for (int e = tid; e < Ez; e += 1024) {
    int col = ei[Ez + e];
    atomicAdd(&disS[col], ew[e]);
    atomicAdd(&cntS[col], 1);
  }
  __syncthreads();
  float d = disS[tid];
  float dis = 1.0f / sqrtf(d);
  if (tid < Nz) ideg[tid] = 1.0f / d;
  __syncthreads();
  disS[tid] = dis;
  // exclusive scan of cnt
  int v0 = cntS[tid];
  scanS[tid] = v0;
  __syncthreads();
  for (int off = 1; off < 1024; off <<= 1) {
    int v = (tid >= off) ? scanS[tid - off] : 0;
    __syncthreads();
    scanS[tid] += v;
    __syncthreads();
  }
  int excl = scanS[tid] - v0;
  roffg[tid] = excl;
  cntg[tid] = v0;
  curS[tid] = excl;
  __syncthreads();
  for (int e = tid; e < Ez; e += 1024) {
    int row = ei[e], col = ei[Ez + e];
    int p = atomicAdd(&curS[col], 1);
    csrs[p] = row;
    csrw[p] = disS[row] * ew[e] * disS[col];
  }
}

// Fold W_gcn into W_ih (blocks 0..1023); blocks 1024..1151 cast Whh -> fp16 with
// row permutation row' = hl*4 + gate (so one 16-row MFMA tile = 4 hl x 4 gates).
__global__ void __launch_bounds__(256) k_fold(const float* __restrict__ Wih,
                                              const float* __restrict__ Wg,
                                              const float* __restrict__ bg,
                                              _Float16* __restrict__ wc,
                                              float* __restrict__ bgc,
                                              const float* __restrict__ Whh,
                                              _Float16* __restrict__ whh16) {
  __shared__ float wgs[Cz * HGz];
  __shared__ float bgs[HGz];
  __shared__ float red[256];
  int tid = threadIdx.x;
  int j = blockIdx.x;
  if (j >= 1024) {
    size_t i = (size_t)(j - 1024) * 256 + tid;  // 32768 half8s
    int row = (int)(i >> 5), c8 = (int)(i & 31);
    int rp = ((row & 255) << 2) | (row >> 8);   // row' = hl*4 + g
    float4 a = ((const float4*)Whh)[i * 2];
    float4 b = ((const float4*)Whh)[i * 2 + 1];
    half8 h;
    h[0] = (_Float16)a.x; h[1] = (_Float16)a.y; h[2] = (_Float16)a.z; h[3] = (_Float16)a.w;
    h[4] = (_Float16)b.x; h[5] = (_Float16)b.y; h[6] = (_Float16)b.z; h[7] = (_Float16)b.w;
    ((half8*)whh16)[(size_t)rp * 32 + c8] = h;
    return;
  }
  if (tid < Cz * HGz) wgs[tid] = Wg[tid];
  if (tid < HGz) bgs[tid] = bg[tid];
  __syncthreads();
  const float* row = Wih + (size_t)j * (Nz * HGz);
  float bacc = 0.f;
  for (int n = tid; n < Nz; n += 256) {
    const float* p = row + n * HGz;
    float w[16];
    float4 v0 = *(const float4*)p, v1 = *(const float4*)(p + 4);
    float4 v2 = *(const float4*)(p + 8), v3 = *(const float4*)(p + 12);
    w[0]=v0.x; w[1]=v0.y; w[2]=v0.z; w[3]=v0.w;
    w[4]=v1.x; w[5]=v1.y; w[6]=v1.z; w[7]=v1.w;
    w[8]=v2.x; w[9]=v2.y; w[10]=v2.z; w[11]=v2.w;
    w[12]=v3.x; w[13]=v3.y; w[14]=v3.z; w[15]=v3.w;
    half8 o;
#pragma unroll
    for (int c = 0; c < Cz; ++c) {
      float s = 0.f;
#pragma unroll
      for (int h = 0; h < HGz; ++h) s += w[h] * wgs[c * HGz + h];
      o[c] = (_Float16)s;
    }
#pragma unroll
    for (int h = 0; h < HGz; ++h) bacc += w[h] * bgs[h];
    *(half8*)(wc + (size_t)j * K2z + n * Cz) = o;
  }
  red[tid] = bacc;
  __syncthreads();
  for (int off = 128; off > 0; off >>= 1) {
    if (tid < off) red[tid] += red[tid + off];
    __syncthreads();
  }
  if (tid == 0) bgc[j] = red[0];
}

// xt: blocks 0..249 = batch-0 rows (ideg*x + CSR neighbor agg); blocks 250..7999 = fp16 cast of x batches 1..31.
__global__ void k_xt(const float* __restrict__ x, const float* __restrict__ ideg,
                     const int* __restrict__ roff, const int* __restrict__ cnt,
                     const int* __restrict__ csrs, const float* __restrict__ csrw,
                     _Float16* __restrict__ xt) {
  if (blockIdx.x >= 250) {
    size_t i = (size_t)(blockIdx.x - 250) * 256 + threadIdx.x;
    const float* src = x + (size_t)Tz * K2z;
    _Float16* dst = xt + (size_t)Tz * K2z;
    float4 a = ((const float4*)src)[i * 2];
    float4 b = ((const float4*)src)[i * 2 + 1];
    half8 h;
    h[0] = (_Float16)a.x; h[1] = (_Float16)a.y; h[2] = (_Float16)a.z; h[3] = (_Float16)a.w;
    h[4] = (_Float16)b.x; h[5] = (_Float16)b.y; h[6] = (_Float16)b.z; h[7] = (_Float16)b.w;
    ((half8*)dst)[i] = h;
    return;
  }
  int g = blockIdx.x * 256 + threadIdx.x;  // t*1000+n
  if (g >= Tz * Nz) return;
  int t = g / Nz, n = g % Nz;
  const float* xp = x + (size_t)g * Cz;
  float4 a = *(const float4*)xp, b = *(const float4*)(xp + 4);
  float id = ideg[n];
  float s[8] = {id*a.x, id*a.y, id*a.z, id*a.w, id*b.x, id*b.y, id*b.z, id*b.w};
  int i0 = roff[n], nc = cnt[n];
  for (int i = i0; i < i0 + nc; ++i) {
    int src = csrs[i];
    float wv = csrw[i];
    const float* q = x + ((size_t)t * Nz + src) * Cz;
    float4 u = *(const float4*)q, v = *(const float4*)(q + 4);
    s[0] += wv * u.x; s[1] += wv * u.y; s[2] += wv * u.z; s[3] += wv * u.w;
    s[4] += wv * v.x; s[5] += wv * v.y; s[6] += wv * v.z; s[7] += wv * v.w;
  }
  half8 h;
#pragma unroll
  for (int c = 0; c < 8; ++c) h[c] = (_Float16)s[c];
  *(half8*)(xt + (size_t)t * K2z + n * Cz) = h;
}

// ---------------- GEMM: preS[z][2048][1024] (fp16) = xt @ Wc^T, uneven split-K=8 ----------------
__global__ void __launch_bounds__(256) k_gemm(const _Float16* __restrict__ A,
                                              const _Float16* __restrict__ Bm,
                                              _Float16* __restrict__ Cp) {
  __shared__ _Float16 As[128 * 32];
  __shared__ _Float16 Bs[128 * 32];
  const int tid = threadIdx.x;
  const int lane = tid & 63;
  const int wave = tid >> 6;
  const int wm = wave & 1, wn = wave >> 1;
  const int quad = lane >> 4, l15 = lane & 15;
  const size_t tm = (size_t)blockIdx.x * 128;
  const size_t tn = (size_t)blockIdx.y * 128;
  const int k0 = blockIdx.z * 1024;
  const int iters = (blockIdx.z < 7) ? 32 : 26;   // 7*1024 + 832 = 8000
  _Float16* Cz_ = Cp + (size_t)blockIdx.z * Mz * G4z;
  const int srow = tid >> 2;
  const int skk = (tid & 3) * 8;
  const _Float16* gA0 = A + (tm + srow) * (size_t)K2z + k0 + skk;
  const _Float16* gA1 = gA0 + 64 * (size_t)K2z;
  const _Float16* gB0 = Bm + (tn + srow) * (size_t)K2z + k0 + skk;
  const _Float16* gB1 = gB0 + 64 * (size_t)K2z;
  _Float16* lA0 = &As[tid * 8];
  _Float16* lA1 = &As[2048 + tid * 8];
  _Float16* lB0 = &Bs[tid * 8];
  _Float16* lB1 = &Bs[2048 + tid * 8];
  floatx4 acc[4][4] = {};
  for (int kt = 0; kt < iters; ++kt) {
    __syncthreads();
    gl_lds16(gA0, lA0);
    gl_lds16(gA1, lA1);
    gl_lds16(gB0, lB0);
    gl_lds16(gB1, lB1);
    gA0 += 32; gA1 += 32; gB0 += 32; gB1 += 32;
    __syncthreads();
    half8 af[4], bf[4];
#pragma unroll
    for (int i = 0; i < 4; ++i)
      af[i] = *(const half8*)&As[(wm * 64 + i * 16 + l15) * 32 + quad * 8];
#pragma unroll
    for (int i = 0; i < 4; ++i)
      bf[i] = *(const half8*)&Bs[(wn * 64 + i * 16 + l15) * 32 + quad * 8];
#pragma unroll
    for (int mi = 0; mi < 4; ++mi)
#pragma unroll
      for (int ni = 0; ni < 4; ++ni)
        acc[mi][ni] = __builtin_amdgcn_mfma_f32_16x16x32_f16(af[mi], bf[ni], acc[mi][ni], 0, 0, 0);
  }
#pragma unroll
  for (int mi = 0; mi < 4; ++mi)
#pragma unroll
    for (int ni = 0; ni < 4; ++ni) {
      size_t r0 = tm + wm * 64 + mi * 16 + quad * 4;
      size_t cc = tn + wn * 64 + ni * 16 + l15;
#pragma unroll
      for (int q = 0; q < 4; ++q) Cz_[(r0 + q) * G4z + cc] = (_Float16)acc[mi][ni][q];
    }
}

// ------- reduce fp16 split-K + biases -> pre[t][b][j'] (fp16), j' = hl*4 + gate -------
__global__ void k_reduce(const _Float16* __restrict__ preS, const float* __restrict__ bih,
                         const float* __restrict__ bhh, const float* __restrict__ bgc,
                         _Float16* __restrict__ preT) {
  int t = blockIdx.x;                      // 0..63
  int j = blockIdx.y * 256 + threadIdx.x;  // 0..1023 ; g = blockIdx.y, hl = threadIdx.x
  float bias = bih[j] + bhh[j] + bgc[j];
  float v[32];
#pragma unroll
  for (int b = 0; b < 32; ++b) v[b] = bias;
  for (int s = 0; s < NSz; ++s) {
    const _Float16* base = preS + (size_t)s * Mz * G4z;
#pragma unroll
    for (int b = 0; b < 32; ++b)
      v[b] += (float)base[((size_t)b * Tz + t) * G4z + j];
  }
#pragma unroll
  for (int b = 0; b < 32; ++b)
    preT[((size_t)t * 32 + b) * G4z + threadIdx.x * 4 + blockIdx.y] = (_Float16)v[b];
}

// ---------------- LSTM v4: 16 blocks = 2 batch-domains x 8 hl-slices ----------------
// W permuted row' = hl*4+g: one 16-row tile = 4 hl x 4 gates. Each wave holds 2 tiles
// = 16 half8 = 64 VGPR of W, PERMANENTLY resident -> zero W traffic per step (no spill,
// no LDS re-read). D-fragment row = quad*4+j gives each lane all 4 gates of one (hl,b):
// pointwise lane-local on all 64 lanes. acc inits from preT (biases folded). h-exchange
// = proven u64 NaN-sentinel protocol: shfl-gather 4 quads -> quad0 stores u64; readers
// poll 4 u64/thread, stage via ds_write_b64. One barrier/step.
// Wait-graph is acyclic (step t needs only step t-1 words; every word has exactly one
// writer; readers skip their own block's words) -> no deadlock; 16 blocks co-resident.
__global__ void __launch_bounds__(256, 1) k_lstmZ(const _Float16* __restrict__ Wp16, // [1024 row'][256]
                                                  const _Float16* __restrict__ preT, // [64][32][1024]
                                                  unsigned long long* __restrict__ hx, // [2][64][16][64]
                                                  float* __restrict__ hlast) {        // [32][256]
  __shared__ _Float16 hb[2][16 * 264];   // [parity][batch16][hl 256 + pad]
  const int tid = threadIdx.x;
  const int w = tid >> 6;
  const int lane = tid & 63;
  const int quad = lane >> 4, l15 = lane & 15;
  const int dom = blockIdx.x >> 3;       // batch domain: batches dom*16 .. dom*16+15
  const int s = blockIdx.x & 7;          // hl slice: hl in [s*32, s*32+32)

  for (int i = tid; i < 2 * 16 * 264; i += 256) ((_Float16*)hb)[i] = (_Float16)0.f;

  // W fragments: wave w, tiles tt=0,1 -> row' base = s*128 + (w*2+tt)*16
  half8 wr0[8], wr1[8];
  {
    const _Float16* s0 = Wp16 + (size_t)(s * 128 + w * 32 + l15) * 256 + quad * 8;
    const _Float16* s1 = s0 + 16 * 256;
#pragma unroll
    for (int kt = 0; kt < 8; ++kt) { wr0[kt] = *(const half8*)(s0 + kt * 32); }
#pragma unroll
    for (int kt = 0; kt < 8; ++kt) { wr1[kt] = *(const half8*)(s1 + kt * 32); }
  }
  const int hl0 = s * 32 + w * 8 + quad;       // tile 0: hl
  const int hl1 = hl0 + 4;                     // tile 1: hl
  const int bl = tid >> 4, hq = tid & 15;      // poll mapping: batch bl, hl-window hq*16
  const bool dopoll = (hq >> 1) != s;          // skip own slice (written locally)
  const int bg = dom * 16;

  float cs0 = 0.f, cs1 = 0.f;
  __syncthreads();

  for (int t = 0; t < Tz; ++t) {
    // pre-activation loads (h-independent): issue before poll
    const _Float16* pp = preT + ((size_t)t * 32 + bg + l15) * G4z;
    half4 pq0 = *(const half4*)(pp + hl0 * 4);
    half4 pq1 = *(const half4*)(pp + hl1 * 4);

    if (t > 0 && dopoll) {
      const unsigned long long* src = hx + (((size_t)dom * 64 + t) * 16 + bl) * 64 + hq * 4;
      unsigned long long* dst = (unsigned long long*)&hb[t & 1][bl * 264 + hq * 16];
#pragma unroll
      for (int w4 = 0; w4 < 4; ++w4) {
        unsigned long long v;
        while ((v = __hip_atomic_load(src + w4, __ATOMIC_RELAXED,
                                      __HIP_MEMORY_SCOPE_AGENT)) == SENT)
          __builtin_amdgcn_s_sleep(2);
        dst[w4] = v;
      }
    }
    __syncthreads();

    floatx4 a0, a1;
    a0[0] = (float)pq0[0]; a0[1] = (float)pq0[1]; a0[2] = (float)pq0[2]; a0[3] = (float)pq0[3];
    a1[0] = (float)pq1[0]; a1[1] = (float)pq1[1]; a1[2] = (float)pq1[2]; a1[3] = (float)pq1[3];
    const _Float16* hrow = &hb[t & 1][l15 * 264 + quad * 8];
#pragma unroll
    for (int kt = 0; kt < 8; ++kt) {
      half8 h8 = *(const half8*)(hrow + kt * 32);
      a0 = __builtin_amdgcn_mfma_f32_16x16x32_f16(wr0[kt], h8, a0, 0, 0, 0);
      a1 = __builtin_amdgcn_mfma_f32_16x16x32_f16(wr1[kt], h8, a1, 0, 0, 0);
    }
    // pointwise: lane-local i,f,g,o (gate = j index of acc)
    unsigned short u0, u1;
    {
      float iv = sigm(a0[0]), fv = sigm(a0[1]), gv = tanhh(a0[2]), ov = sigm(a0[3]);
      float cn = fv * cs0 + iv * gv; cs0 = cn;
      float hn = ov * tanhh(cn);
      u0 = __builtin_bit_cast(unsigned short, (_Float16)hn);
      if (t == Tz - 1) hlast[(size_t)(bg + l15) * HLz + hl0] = hn;
    }
    {
      float iv = sigm(a1[0]), fv = sigm(a1[1]), gv = tanhh(a1[2]), ov = sigm(a1[3]);
      float cn = fv * cs1 + iv * gv; cs1 = cn;
      float hn = ov * tanhh(cn);
      u1 = __builtin_bit_cast(unsigned short, (_Float16)hn);
      if (t == Tz - 1) hlast[(size_t)(bg + l15) * HLz + hl1] = hn;
    }
    if (t < Tz - 1) {
      // gather quads 1..3 into quad0, publish u64 words (b=l15, word = s*8 + w*2 + tt)
      int i0 = u0, i1 = u1;
      int g01 = __shfl(i0, l15 + 16, 64), g02 = __shfl(i0, l15 + 32, 64), g03 = __shfl(i0, l15 + 48, 64);
      int g11 = __shfl(i1, l15 + 16, 64), g12 = __shfl(i1, l15 + 32, 64), g13 = __shfl(i1, l15 + 48, 64);
      if (quad == 0) {
        unsigned long long v0 = (unsigned long long)(unsigned short)i0 |
                                ((unsigned long long)(unsigned short)g01 << 16) |
                                ((unsigned long long)(unsigned short)g02 << 32) |
                                ((unsigned long long)(unsigned short)g03 << 48);
        unsigned long long v1 = (unsigned long long)(unsigned short)i1 |
                                ((unsigned long long)(unsigned short)g11 << 16) |
                                ((unsigned long long)(unsigned short)g12 << 32) |
                                ((unsigned long long)(unsigned short)g13 << 48);
        unsigned long long* pb = hx + (((size_t)dom * 64 + t + 1) * 16 + l15) * 64 + s * 8 + w * 2;
        __hip_atomic_store(pb, v0, __ATOMIC_RELAXED, __HIP_MEMORY_SCOPE_AGENT);
        __hip_atomic_store(pb + 1, v1, __ATOMIC_RELAXED, __HIP_MEMORY_SCOPE_AGENT);
      }
      // own h into next-parity LDS (all lanes)
      _Float16* hbn = &hb[(t + 1) & 1][l15 * 264];
      hbn[hl0] = __builtin_bit_cast(_Float16, u0);
      hbn[hl1] = __builtin_bit_cast(_Float16, u1);
    }
  }
}

// out[b,o] = h_last[b,:] @ W_proj[o,:] + b_proj[o]
__global__ void k_proj(const float* __restrict__ hlast, const float* __restrict__ Wp,
                       const float* __restrict__ bp, float* __restrict__ out) {
  int idx = blockIdx.x * 256 + threadIdx.x;
  if (idx >= Bz * OUTz) return;
  int b = idx / OUTz, o = idx % OUTz;
  const float* h = hlast + (size_t)b * HLz;
  const float* wr = Wp + (size_t)o * HLz;
  float s = 0.f;
  for (int k = 0; k < HLz; k += 4) {
    float4 hv = *(const float4*)&h[k];
    float4 wv = *(const float4*)&wr[k];
    s += hv.x * wv.x + hv.y * wv.y + hv.z * wv.z + hv.w * wv.w;
  }
  out[idx] = s + bp[o];
}

extern "C" void kernel_launch(void* const* d_in, const int* in_sizes, int n_in,
                              void* d_out, int out_size, void* d_ws, size_t ws_size,
                              hipStream_t stream) {
  const float* x   = (const float*)d_in[0];
  const int*   ei  = (const int*)d_in[1];
  const float* ew  = (const float*)d_in[2];
  const float* Wg  = (const float*)d_in[3];
  const float* bg  = (const float*)d_in[4];
  const float* Wih = (const float*)d_in[5];
  const float* Whh = (const float*)d_in[6];
  const float* bih = (const float*)d_in[7];
  const float* bhh = (const float*)d_in[8];
  const float* Wp  = (const float*)d_in[9];
  const float* bp  = (const float*)d_in[10];
  float* out = (float*)d_out;
  char* ws = (char*)d_ws;
  if (ws_size < WS_NEED) return;

  float* ideg  = (float*)(ws + OFF_IDEG);
  int*   cnt   = (int*)(ws + OFF_CNT);
  int*   roff  = (int*)(ws + OFF_ROFF);
  int*   csrs  = (int*)(ws + OFF_CSRS);
  float* csrw  = (float*)(ws + OFF_CSRW);
  float* hlast = (float*)(ws + OFF_HLAST);
  _Float16* preT  = (_Float16*)(ws + OFF_PRE16T);
  _Float16* whh16 = (_Float16*)(ws + OFF_WHH16);
  unsigned long long* hx = (unsigned long long*)(ws + OFF_HX);
  float* bgc   = (float*)(ws + OFF_BGC);
  _Float16* xt    = (_Float16*)(ws + OFF_XT);
  _Float16* wc    = (_Float16*)(ws + OFF_WC);
  _Float16* preS  = (_Float16*)(ws + OFF_PRES);

  // hx = NaN sentinel (byte-uniform); slot t=0 is never read (h0=0 handled in-kernel)
  hipMemsetAsync(ws + OFF_HX, 0x7E, (size_t)2 * 64 * 16 * 64 * 8, stream);

  k_prep<<<1, 1024, 0, stream>>>(ei, ew, ideg, cnt, roff, csrs, csrw);
  k_fold<<<1152, 256, 0, stream>>>(Wih, Wg, bg, wc, bgc, Whh, whh16);
  k_xt<<<8000, 256, 0, stream>>>(x, ideg, roff, cnt, csrs, csrw, xt);
  k_gemm<<<dim3(16, 8, NSz), 256, 0, stream>>>(xt, wc, preS);
  k_reduce<<<dim3(Tz, 4), 256, 0, stream>>>(preS, bih, bhh, bgc, preT);
  k_lstmZ<<<16, 256, 0, stream>>>(whh16, preT, hx, hlast);
  k_proj<<<3, 256, 0, stream>>>(hlast, Wp, bp, out);
}

// Round 8
// 439.330 us; speedup vs baseline: 1.4263x; 1.0400x over previous
//
#include <hip/hip_runtime.h>
#include <stdint.h>

// Problem constants
#define Bz 32
#define Tz 64
#define Nz 1000
#define Cz 8
#define HGz 16
#define HLz 256
#define OUTz 24
#define Ez 16000
#define K2z 8000   // N*C (folded GEMM K)
#define Mz 2048    // B*T
#define G4z 1024   // 4*HL
#define NSz 8      // split-K count

using half8  = __attribute__((ext_vector_type(8))) _Float16;
using half4  = __attribute__((ext_vector_type(4))) _Float16;
using floatx4 = __attribute__((ext_vector_type(4))) float;

#define SENT 0x7E7E7E7E7E7E7E7EULL  // 4x fp16 NaN, memset-able byte 0x7E

// ---- Workspace layout (bytes) ----
static const size_t OFF_IDEG   = 4096;      // fp32 [1000]
static const size_t OFF_CNT    = 73728;     // int  [1024]
static const size_t OFF_ROFF   = 77824;     // int  [1024]
static const size_t OFF_CSRS   = 86016;     // int  [16000]
static const size_t OFF_CSRW   = 151552;    // fp32 [16000]
static const size_t OFF_HLAST  = 217088;    // fp32 [32][256]
static const size_t OFF_PRE16T = 249856;    // fp16 [64][32][1024] j'=hl*4+g   4,194,304
static const size_t OFF_WHH16  = 4444160;   // fp16 [1024][256] row'=hl*4+g     524,288
static const size_t OFF_HX     = 4968448;   // u64  [2][64][16][64]           1,048,576
static const size_t OFF_BGC    = 6037504;   // fp32 [1024]
static const size_t OFF_XT     = 6041600;   // fp16 [2048][8000]   32,768,000
static const size_t OFF_WC     = 38809600;  // fp16 [1024][8000]   16,384,000
static const size_t OFF_PRES   = 55193600;  // fp16 [8][2048][1024] 33,554,432
static const size_t WS_NEED    = 88748032;

__device__ __forceinline__ void gl_lds16(const void* g, void* l) {
  __builtin_amdgcn_global_load_lds(
      (__attribute__((address_space(1))) void*)(void*)g,
      (__attribute__((address_space(3))) void*)l, 16, 0, 0);
}

__device__ __forceinline__ float sigm(float x) { return 1.0f / (1.0f + __expf(-x)); }
__device__ __forceinline__ float tanhh(float x) { return 1.0f - 2.0f / (__expf(2.0f * x) + 1.0f); }

// ---------------- fused GCN prep: deg, norm, CSR (one WG, LDS atomics + LDS scan) ----------------
__global__ void __launch_bounds__(1024) k_prep(const int* __restrict__ ei,
                                               const float* __restrict__ ew,
                                               float* __restrict__ ideg,
                                               int* __restrict__ cntg,
                                               int* __restrict__ roffg,
                                               int* __restrict__ csrs,
                                               float* __restrict__ csrw) {
  __shared__ float disS[1024];   // deg, then 1/sqrt(deg)
  __shared__ int   cntS[1024];
  __shared__ int   curS[1024];
  __shared__ int   scanS[1024];
  int tid = threadIdx.x;
  disS[tid] = 1.0f;
  cntS[tid] = 0;
  __syncthreads();
  for (int e = tid; e < Ez; e += 1024) {
    int col = ei[Ez + e];
    atomicAdd(&disS[col], ew[e]);
    atomicAdd(&cntS[col], 1);
  }
  __syncthreads();
  float d = disS[tid];
  float dis = 1.0f / sqrtf(d);
  if (tid < Nz) ideg[tid] = 1.0f / d;
  __syncthreads();
  disS[tid] = dis;
  // exclusive scan of cnt
  int v0 = cntS[tid];
  scanS[tid] = v0;
  __syncthreads();
  for (int off = 1; off < 1024; off <<= 1) {
    int v = (tid >= off) ? scanS[tid - off] : 0;
    __syncthreads();
    scanS[tid] += v;
    __syncthreads();
  }
  int excl = scanS[tid] - v0;
  roffg[tid] = excl;
  cntg[tid] = v0;
  curS[tid] = excl;
  __syncthreads();
  for (int e = tid; e < Ez; e += 1024) {
    int row = ei[e], col = ei[Ez + e];
    int p = atomicAdd(&curS[col], 1);
    csrs[p] = row;
    csrw[p] = disS[row] * ew[e] * disS[col];
  }
}

// Fold W_gcn into W_ih (blocks 0..1023); blocks 1024..1151 cast Whh -> fp16 with
// row permutation row' = hl*4 + gate (so one 16-row MFMA tile = 4 hl x 4 gates).
__global__ void __launch_bounds__(256) k_fold(const float* __restrict__ Wih,
                                              const float* __restrict__ Wg,
                                              const float* __restrict__ bg,
                                              _Float16* __restrict__ wc,
                                              float* __restrict__ bgc,
                                              const float* __restrict__ Whh,
                                              _Float16* __restrict__ whh16) {
  __shared__ float wgs[Cz * HGz];
  __shared__ float bgs[HGz];
  __shared__ float red[256];
  int tid = threadIdx.x;
  int j = blockIdx.x;
  if (j >= 1024) {
    size_t i = (size_t)(j - 1024) * 256 + tid;  // 32768 half8s
    int row = (int)(i >> 5), c8 = (int)(i & 31);
    int rp = ((row & 255) << 2) | (row >> 8);   // row' = hl*4 + g
    float4 a = ((const float4*)Whh)[i * 2];
    float4 b = ((const float4*)Whh)[i * 2 + 1];
    half8 h;
    h[0] = (_Float16)a.x; h[1] = (_Float16)a.y; h[2] = (_Float16)a.z; h[3] = (_Float16)a.w;
    h[4] = (_Float16)b.x; h[5] = (_Float16)b.y; h[6] = (_Float16)b.z; h[7] = (_Float16)b.w;
    ((half8*)whh16)[(size_t)rp * 32 + c8] = h;
    return;
  }
  if (tid < Cz * HGz) wgs[tid] = Wg[tid];
  if (tid < HGz) bgs[tid] = bg[tid];
  __syncthreads();
  const float* row = Wih + (size_t)j * (Nz * HGz);
  float bacc = 0.f;
  for (int n = tid; n < Nz; n += 256) {
    const float* p = row + n * HGz;
    float w[16];
    float4 v0 = *(const float4*)p, v1 = *(const float4*)(p + 4);
    float4 v2 = *(const float4*)(p + 8), v3 = *(const float4*)(p + 12);
    w[0]=v0.x; w[1]=v0.y; w[2]=v0.z; w[3]=v0.w;
    w[4]=v1.x; w[5]=v1.y; w[6]=v1.z; w[7]=v1.w;
    w[8]=v2.x; w[9]=v2.y; w[10]=v2.z; w[11]=v2.w;
    w[12]=v3.x; w[13]=v3.y; w[14]=v3.z; w[15]=v3.w;
    half8 o;
#pragma unroll
    for (int c = 0; c < Cz; ++c) {
      float s = 0.f;
#pragma unroll
      for (int h = 0; h < HGz; ++h) s += w[h] * wgs[c * HGz + h];
      o[c] = (_Float16)s;
    }
#pragma unroll
    for (int h = 0; h < HGz; ++h) bacc += w[h] * bgs[h];
    *(half8*)(wc + (size_t)j * K2z + n * Cz) = o;
  }
  red[tid] = bacc;
  __syncthreads();
  for (int off = 128; off > 0; off >>= 1) {
    if (tid < off) red[tid] += red[tid + off];
    __syncthreads();
  }
  if (tid == 0) bgc[j] = red[0];
}

// xt: blocks 0..249 = batch-0 rows (ideg*x + CSR neighbor agg); blocks 250..7999 = fp16 cast of x batches 1..31.
__global__ void k_xt(const float* __restrict__ x, const float* __restrict__ ideg,
                     const int* __restrict__ roff, const int* __restrict__ cnt,
                     const int* __restrict__ csrs, const float* __restrict__ csrw,
                     _Float16* __restrict__ xt) {
  if (blockIdx.x >= 250) {
    size_t i = (size_t)(blockIdx.x - 250) * 256 + threadIdx.x;
    const float* src = x + (size_t)Tz * K2z;
    _Float16* dst = xt + (size_t)Tz * K2z;
    float4 a = ((const float4*)src)[i * 2];
    float4 b = ((const float4*)src)[i * 2 + 1];
    half8 h;
    h[0] = (_Float16)a.x; h[1] = (_Float16)a.y; h[2] = (_Float16)a.z; h[3] = (_Float16)a.w;
    h[4] = (_Float16)b.x; h[5] = (_Float16)b.y; h[6] = (_Float16)b.z; h[7] = (_Float16)b.w;
    ((half8*)dst)[i] = h;
    return;
  }
  int g = blockIdx.x * 256 + threadIdx.x;  // t*1000+n
  if (g >= Tz * Nz) return;
  int t = g / Nz, n = g % Nz;
  const float* xp = x + (size_t)g * Cz;
  float4 a = *(const float4*)xp, b = *(const float4*)(xp + 4);
  float id = ideg[n];
  float s[8] = {id*a.x, id*a.y, id*a.z, id*a.w, id*b.x, id*b.y, id*b.z, id*b.w};
  int i0 = roff[n], nc = cnt[n];
  for (int i = i0; i < i0 + nc; ++i) {
    int src = csrs[i];
    float wv = csrw[i];
    const float* q = x + ((size_t)t * Nz + src) * Cz;
    float4 u = *(const float4*)q, v = *(const float4*)(q + 4);
    s[0] += wv * u.x; s[1] += wv * u.y; s[2] += wv * u.z; s[3] += wv * u.w;
    s[4] += wv * v.x; s[5] += wv * v.y; s[6] += wv * v.z; s[7] += wv * v.w;
  }
  half8 h;
#pragma unroll
  for (int c = 0; c < 8; ++c) h[c] = (_Float16)s[c];
  *(half8*)(xt + (size_t)t * K2z + n * Cz) = h;
}

// ---------------- GEMM: preS[z][2048][1024] (fp16) = xt @ Wc^T, uneven split-K=8 ----------------
__global__ void __launch_bounds__(256) k_gemm(const _Float16* __restrict__ A,
                                              const _Float16* __restrict__ Bm,
                                              _Float16* __restrict__ Cp) {
  __shared__ _Float16 As[128 * 32];
  __shared__ _Float16 Bs[128 * 32];
  const int tid = threadIdx.x;
  const int lane = tid & 63;
  const int wave = tid >> 6;
  const int wm = wave & 1, wn = wave >> 1;
  const int quad = lane >> 4, l15 = lane & 15;
  const size_t tm = (size_t)blockIdx.x * 128;
  const size_t tn = (size_t)blockIdx.y * 128;
  const int k0 = blockIdx.z * 1024;
  const int iters = (blockIdx.z < 7) ? 32 : 26;   // 7*1024 + 832 = 8000
  _Float16* Cz_ = Cp + (size_t)blockIdx.z * Mz * G4z;
  const int srow = tid >> 2;
  const int skk = (tid & 3) * 8;
  const _Float16* gA0 = A + (tm + srow) * (size_t)K2z + k0 + skk;
  const _Float16* gA1 = gA0 + 64 * (size_t)K2z;
  const _Float16* gB0 = Bm + (tn + srow) * (size_t)K2z + k0 + skk;
  const _Float16* gB1 = gB0 + 64 * (size_t)K2z;
  _Float16* lA0 = &As[tid * 8];
  _Float16* lA1 = &As[2048 + tid * 8];
  _Float16* lB0 = &Bs[tid * 8];
  _Float16* lB1 = &Bs[2048 + tid * 8];
  floatx4 acc[4][4] = {};
  for (int kt = 0; kt < iters; ++kt) {
    __syncthreads();
    gl_lds16(gA0, lA0);
    gl_lds16(gA1, lA1);
    gl_lds16(gB0, lB0);
    gl_lds16(gB1, lB1);
    gA0 += 32; gA1 += 32; gB0 += 32; gB1 += 32;
    __syncthreads();
    half8 af[4], bf[4];
#pragma unroll
    for (int i = 0; i < 4; ++i)
      af[i] = *(const half8*)&As[(wm * 64 + i * 16 + l15) * 32 + quad * 8];
#pragma unroll
    for (int i = 0; i < 4; ++i)
      bf[i] = *(const half8*)&Bs[(wn * 64 + i * 16 + l15) * 32 + quad * 8];
#pragma unroll
    for (int mi = 0; mi < 4; ++mi)
#pragma unroll
      for (int ni = 0; ni < 4; ++ni)
        acc[mi][ni] = __builtin_amdgcn_mfma_f32_16x16x32_f16(af[mi], bf[ni], acc[mi][ni], 0, 0, 0);
  }
#pragma unroll
  for (int mi = 0; mi < 4; ++mi)
#pragma unroll
    for (int ni = 0; ni < 4; ++ni) {
      size_t r0 = tm + wm * 64 + mi * 16 + quad * 4;
      size_t cc = tn + wn * 64 + ni * 16 + l15;
#pragma unroll
      for (int q = 0; q < 4; ++q) Cz_[(r0 + q) * G4z + cc] = (_Float16)acc[mi][ni][q];
    }
}

// ------- reduce fp16 split-K + biases -> pre[t][b][j'] (fp16), j' = hl*4 + gate -------
__global__ void k_reduce(const _Float16* __restrict__ preS, const float* __restrict__ bih,
                         const float* __restrict__ bhh, const float* __restrict__ bgc,
                         _Float16* __restrict__ preT) {
  int t = blockIdx.x;                      // 0..63
  int j = blockIdx.y * 256 + threadIdx.x;  // 0..1023 ; g = blockIdx.y, hl = threadIdx.x
  float bias = bih[j] + bhh[j] + bgc[j];
  float v[32];
#pragma unroll
  for (int b = 0; b < 32; ++b) v[b] = bias;
  for (int s = 0; s < NSz; ++s) {
    const _Float16* base = preS + (size_t)s * Mz * G4z;
#pragma unroll
    for (int b = 0; b < 32; ++b)
      v[b] += (float)base[((size_t)b * Tz + t) * G4z + j];
  }
#pragma unroll
  for (int b = 0; b < 32; ++b)
    preT[((size_t)t * 32 + b) * G4z + threadIdx.x * 4 + blockIdx.y] = (_Float16)v[b];
}

// ---------------- LSTM: R4-measured k_lstmZ, single change = parallel 4-load poll ----------------
// 16 blocks = 2 batch-domains x 8 hl-slices; W fragments 64 VGPR resident/lane (row'=hl*4+g
// permutation -> D-fragment hands each lane all 4 gates of one (hl,batch)); u64 NaN-sentinel
// h-exchange. Poll issues all 4 u64 loads back-to-back per iteration (one LLC round trip
// detects all four) instead of 4 serially control-dependent sentinel waits.
__global__ void __launch_bounds__(256, 1) k_lstmZ(const _Float16* __restrict__ Wp16, // [1024 row'][256]
                                                  const _Float16* __restrict__ preT, // [64][32][1024]
                                                  unsigned long long* __restrict__ hx, // [2][64][16][64]
                                                  float* __restrict__ hlast) {        // [32][256]
  __shared__ _Float16 hb[2][16 * 264];   // [parity][batch16][hl 256 + pad]
  const int tid = threadIdx.x;
  const int w = tid >> 6;
  const int lane = tid & 63;
  const int quad = lane >> 4, l15 = lane & 15;
  const int dom = blockIdx.x >> 3;       // batch domain: batches dom*16 .. dom*16+15
  const int s = blockIdx.x & 7;          // hl slice: hl in [s*32, s*32+32)

  for (int i = tid; i < 2 * 16 * 264; i += 256) ((_Float16*)hb)[i] = (_Float16)0.f;

  // W fragments: wave w, tiles tt=0,1 -> row' base = s*128 + (w*2+tt)*16
  half8 wr0[8], wr1[8];
  {
    const _Float16* s0 = Wp16 + (size_t)(s * 128 + w * 32 + l15) * 256 + quad * 8;
    const _Float16* s1 = s0 + 16 * 256;
#pragma unroll
    for (int kt = 0; kt < 8; ++kt) { wr0[kt] = *(const half8*)(s0 + kt * 32); }
#pragma unroll
    for (int kt = 0; kt < 8; ++kt) { wr1[kt] = *(const half8*)(s1 + kt * 32); }
  }
  const int hl0 = s * 32 + w * 8 + quad;       // tile 0: hl
  const int hl1 = hl0 + 4;                     // tile 1: hl
  const int bl = tid >> 4, hq = tid & 15;      // poll mapping: batch bl, hl-window hq*16
  const bool dopoll = (hq >> 1) != s;          // skip own slice (written locally)
  const int bg = dom * 16;

  float cs0 = 0.f, cs1 = 0.f;
  __syncthreads();

  for (int t = 0; t < Tz; ++t) {
    // pre-activation loads (h-independent): issue before poll
    const _Float16* pp = preT + ((size_t)t * 32 + bg + l15) * G4z;
    half4 pq0 = *(const half4*)(pp + hl0 * 4);
    half4 pq1 = *(const half4*)(pp + hl1 * 4);

    if (t > 0 && dopoll) {
      const unsigned long long* src = hx + (((size_t)dom * 64 + t) * 16 + bl) * 64 + hq * 4;
      unsigned long long v0, v1, v2, v3;
      for (;;) {
        v0 = __hip_atomic_load(src + 0, __ATOMIC_RELAXED, __HIP_MEMORY_SCOPE_AGENT);
        v1 = __hip_atomic_load(src + 1, __ATOMIC_RELAXED, __HIP_MEMORY_SCOPE_AGENT);
        v2 = __hip_atomic_load(src + 2, __ATOMIC_RELAXED, __HIP_MEMORY_SCOPE_AGENT);
        v3 = __hip_atomic_load(src + 3, __ATOMIC_RELAXED, __HIP_MEMORY_SCOPE_AGENT);
        if (v0 != SENT && v1 != SENT && v2 != SENT && v3 != SENT) break;
        __builtin_amdgcn_s_sleep(2);
      }
      unsigned long long* dst = (unsigned long long*)&hb[t & 1][bl * 264 + hq * 16];
      dst[0] = v0; dst[1] = v1; dst[2] = v2; dst[3] = v3;
    }
    __syncthreads();

    floatx4 a0, a1;
    a0[0] = (float)pq0[0]; a0[1] = (float)pq0[1]; a0[2] = (float)pq0[2]; a0[3] = (float)pq0[3];
    a1[0] = (float)pq1[0]; a1[1] = (float)pq1[1]; a1[2] = (float)pq1[2]; a1[3] = (float)pq1[3];
    const _Float16* hrow = &hb[t & 1][l15 * 264 + quad * 8];
#pragma unroll
    for (int kt = 0; kt < 8; ++kt) {
      half8 h8 = *(const half8*)(hrow + kt * 32);
      a0 = __builtin_amdgcn_mfma_f32_16x16x32_f16(wr0[kt], h8, a0, 0, 0, 0);
      a1 = __builtin_amdgcn_mfma_f32_16x16x32_f16(wr1[kt], h8, a1, 0, 0, 0);
    }
    // pointwise: lane-local i,f,g,o (gate = acc component)
    unsigned short u0, u1;
    {
      float iv = sigm(a0[0]), fv = sigm(a0[1]), gv = tanhh(a0[2]), ov = sigm(a0[3]);
      float cn = fv * cs0 + iv * gv; cs0 = cn;
      float hn = ov * tanhh(cn);
      u0 = __builtin_bit_cast(unsigned short, (_Float16)hn);
      if (t == Tz - 1) hlast[(size_t)(bg + l15) * HLz + hl0] = hn;
    }
    {
      float iv = sigm(a1[0]), fv = sigm(a1[1]), gv = tanhh(a1[2]), ov = sigm(a1[3]);
      float cn = fv * cs1 + iv * gv; cs1 = cn;
      float hn = ov * tanhh(cn);
      u1 = __builtin_bit_cast(unsigned short, (_Float16)hn);
      if (t == Tz - 1) hlast[(size_t)(bg + l15) * HLz + hl1] = hn;
    }
    if (t < Tz - 1) {
      // gather quads 1..3 into quad0, publish u64 words (b=l15, word = s*8 + w*2 + tt)
      int i0 = u0, i1 = u1;
      int g01 = __shfl(i0, l15 + 16, 64), g02 = __shfl(i0, l15 + 32, 64), g03 = __shfl(i0, l15 + 48, 64);
      int g11 = __shfl(i1, l15 + 16, 64), g12 = __shfl(i1, l15 + 32, 64), g13 = __shfl(i1, l15 + 48, 64);
      if (quad == 0) {
        unsigned long long v0 = (unsigned long long)(unsigned short)i0 |
                                ((unsigned long long)(unsigned short)g01 << 16) |
                                ((unsigned long long)(unsigned short)g02 << 32) |
                                ((unsigned long long)(unsigned short)g03 << 48);
        unsigned long long v1 = (unsigned long long)(unsigned short)i1 |
                                ((unsigned long long)(unsigned short)g11 << 16) |
                                ((unsigned long long)(unsigned short)g12 << 32) |
                                ((unsigned long long)(unsigned short)g13 << 48);
        unsigned long long* pb = hx + (((size_t)dom * 64 + t + 1) * 16 + l15) * 64 + s * 8 + w * 2;
        __hip_atomic_store(pb, v0, __ATOMIC_RELAXED, __HIP_MEMORY_SCOPE_AGENT);
        __hip_atomic_store(pb + 1, v1, __ATOMIC_RELAXED, __HIP_MEMORY_SCOPE_AGENT);
      }
      // own h into next-parity LDS (all lanes)
      _Float16* hbn = &hb[(t + 1) & 1][l15 * 264];
      hbn[hl0] = __builtin_bit_cast(_Float16, u0);
      hbn[hl1] = __builtin_bit_cast(_Float16, u1);
    }
  }
}

// out[b,o] = h_last[b,:] @ W_proj[o,:] + b_proj[o]
__global__ void k_proj(const float* __restrict__ hlast, const float* __restrict__ Wp,
                       const float* __restrict__ bp, float* __restrict__ out) {
  int idx = blockIdx.x * 256 + threadIdx.x;
  if (idx >= Bz * OUTz) return;
  int b = idx / OUTz, o = idx % OUTz;
  const float* h = hlast + (size_t)b * HLz;
  const float* wr = Wp + (size_t)o * HLz;
  float s = 0.f;
  for (int k = 0; k < HLz; k += 4) {
    float4 hv = *(const float4*)&h[k];
    float4 wv = *(const float4*)&wr[k];
    s += hv.x * wv.x + hv.y * wv.y + hv.z * wv.z + hv.w * wv.w;
  }
  out[idx] = s + bp[o];
}

extern "C" void kernel_launch(void* const* d_in, const int* in_sizes, int n_in,
                              void* d_out, int out_size, void* d_ws, size_t ws_size,
                              hipStream_t stream) {
  const float* x   = (const float*)d_in[0];
  const int*   ei  = (const int*)d_in[1];
  const float* ew  = (const float*)d_in[2];
  const float* Wg  = (const float*)d_in[3];
  const float* bg  = (const float*)d_in[4];
  const float* Wih = (const float*)d_in[5];
  const float* Whh = (const float*)d_in[6];
  const float* bih = (const float*)d_in[7];
  const float* bhh = (const float*)d_in[8];
  const float* Wp  = (const float*)d_in[9];
  const float* bp  = (const float*)d_in[10];
  float* out = (float*)d_out;
  char* ws = (char*)d_ws;
  if (ws_size < WS_NEED) return;

  float* ideg  = (float*)(ws + OFF_IDEG);
  int*   cnt   = (int*)(ws + OFF_CNT);
  int*   roff  = (int*)(ws + OFF_ROFF);
  int*   csrs  = (int*)(ws + OFF_CSRS);
  float* csrw  = (float*)(ws + OFF_CSRW);
  float* hlast = (float*)(ws + OFF_HLAST);
  _Float16* preT  = (_Float16*)(ws + OFF_PRE16T);
  _Float16* whh16 = (_Float16*)(ws + OFF_WHH16);
  unsigned long long* hx = (unsigned long long*)(ws + OFF_HX);
  float* bgc   = (float*)(ws + OFF_BGC);
  _Float16* xt    = (_Float16*)(ws + OFF_XT);
  _Float16* wc    = (_Float16*)(ws + OFF_WC);
  _Float16* preS  = (_Float16*)(ws + OFF_PRES);

  // hx = NaN sentinel (byte-uniform); slot t=0 is never read (h0=0 handled in-kernel)
  hipMemsetAsync(ws + OFF_HX, 0x7E, (size_t)2 * 64 * 16 * 64 * 8, stream);

  k_prep<<<1, 1024, 0, stream>>>(ei, ew, ideg, cnt, roff, csrs, csrw);
  k_fold<<<1152, 256, 0, stream>>>(Wih, Wg, bg, wc, bgc, Whh, whh16);
  k_xt<<<8000, 256, 0, stream>>>(x, ideg, roff, cnt, csrs, csrw, xt);
  k_gemm<<<dim3(16, 8, NSz), 256, 0, stream>>>(xt, wc, preS);
  k_reduce<<<dim3(Tz, 4), 256, 0, stream>>>(preS, bih, bhh, bgc, preT);
  k_lstmZ<<<16, 256, 0, stream>>>(whh16, preT, hx, hlast);
  k_proj<<<3, 256, 0, stream>>>(hlast, Wp, bp, out);
}